// Round 8
// baseline (290.652 us; speedup 1.0000x reference)
//
#include <hip/hip_runtime.h>
#include <math.h>

// FlowLevel: DIM=2, half=1 -> per-layer coupling depends on scalar v = z_b.
// t(v) and u(v) (pre-sigmoid) are piecewise-LINEAR in v (ReLU MLP).
// Tabulate (t, dt/dv, u, du/dv) per node; apply reconstructs with two
// tangent lines (exact for <=1 kink per cell).
//
// Build kernel v6b: tile-constant ReLU gates (v6) with the mixed-correction
// weight index FIXED (w_kj = fc2_w[k*128+j]; v6 read the transpose).

constexpr int kDepth = 10;
constexpr int kWidth = 128;
constexpr float kVMin = -24.0f;
constexpr float kVMax =  24.0f;

__global__ __launch_bounds__(256) void build_tables_kernel(
    const float* __restrict__ an_scale,
    const float* __restrict__ conv_w,
    const float* __restrict__ fc1_w, const float* __restrict__ fc1_b,
    const float* __restrict__ an1_scale, const float* __restrict__ an1_bias,
    const float* __restrict__ fc2_w, const float* __restrict__ fc2_b,
    const float* __restrict__ an2_scale, const float* __restrict__ an2_bias,
    const float* __restrict__ fc3_w, const float* __restrict__ fc3_b,
    const float* __restrict__ lsf,
    int tabN,
    float4* __restrict__ tab, float* __restrict__ extra)
{
  __shared__ float  sGOn[128], sBOn[128];   // gated g / beta (0 if not fully-on)
  __shared__ float  sPc[128], sPe[128];     // phase-A partials (j-half 1)
  __shared__ float4 sK[128];                // per-k folded constants
  __shared__ float4 sMix[128];              // mixed-j list: (g, beta, j, -)
  __shared__ int    sCnt[2];

  const int bpl   = tabN >> 6;                 // blocks (tiles) per layer
  const int layer = blockIdx.x / bpl;
  const int node0 = (blockIdx.x % bpl) * 64;
  const int t     = threadIdx.x;
  const float dv  = (kVMax - kVMin) / (float)(tabN - 1);
  const float vlo = kVMin + dv * (float)node0;
  const float vhi = kVMin + dv * (float)(node0 + 63);

  // ---- phase 0: gate classification + deterministic mixed-list scan ----
  bool mix = false; float g = 0.f, b = 0.f;
  if (t < 128) {
    const float s1 = an1_scale[layer*kWidth + t];
    g = fc1_w[layer*kWidth + t] / s1;
    b = (fc1_b[layer*kWidth + t] - an1_bias[layer*kWidth + t]) / s1;
    const bool onL = fmaf(vlo, g, b) > 0.0f;
    const bool onH = fmaf(vhi, g, b) > 0.0f;
    const bool full = onL && onH;
    mix = (onL != onH);
    sGOn[t] = full ? g : 0.0f;
    sBOn[t] = full ? b : 0.0f;
  }
  {
    const unsigned long long m = __ballot(mix);
    const int lane = t & 63, wv = t >> 6;
    const int pos = (int)__popcll(m & ((1ull << lane) - 1ull));
    if (wv < 2 && lane == 0) sCnt[wv] = (int)__popcll(m);
    __syncthreads();
    if (mix) sMix[(wv ? sCnt[0] : 0) + pos] = make_float4(g, b, __int_as_float(t), 0.0f);
  }
  __syncthreads();
  const int nmix = sCnt[0] + sCnt[1];

  // ---- phase A: per-tile dots c_k, e_k over fully-on j (once per tile) ----
  {
    const int k = t & 127, jh = t >> 7;          // j-half 0: j 0..63, 1: 64..127
    const float4* wrow =
        (const float4*)(fc2_w + (size_t)layer * kWidth * kWidth + (size_t)k * kWidth + jh * 64);
    float c = 0.0f, e = 0.0f;
#pragma unroll
    for (int jc = 0; jc < 16; ++jc) {
      float4 w  = wrow[jc];
      float4 g4 = ((const float4*)sGOn)[jh*16 + jc];
      float4 b4 = ((const float4*)sBOn)[jh*16 + jc];
      c = fmaf(g4.w, w.w, fmaf(g4.z, w.z, fmaf(g4.y, w.y, fmaf(g4.x, w.x, c))));
      e = fmaf(b4.w, w.w, fmaf(b4.z, w.z, fmaf(b4.y, w.y, fmaf(b4.x, w.x, e))));
    }
    if (jh) { sPc[k] = c; sPe[k] = e; }
    __syncthreads();
    if (t < 128) {
      c += sPc[t]; e += sPe[t];
      const float si = 1.0f / an2_scale[layer*kWidth + t];
      const float bz = fc2_b[layer*kWidth + t] - an2_bias[layer*kWidth + t];
      sK[t] = make_float4(c, e + bz,
                          fc3_w[layer*2*kWidth + t] * si,
                          fc3_w[layer*2*kWidth + kWidth + t] * si);
    }
  }
  __syncthreads();

  // ---- phase B: per-node evaluation (exact; mixed corrections per node) ----
  {
    const int node = t >> 2, kq = t & 3;         // 4 threads per node, 32 k each
    const float v = kVMin + dv * (float)(node0 + node);
    const float* wl = fc2_w + (size_t)layer * kWidth * kWidth;
    float o0 = 0.f, o1 = 0.f, p0 = 0.f, p1 = 0.f;
#pragma unroll 4
    for (int k = kq*32; k < kq*32 + 32; ++k) {
      float4 K = sK[k];                          // LDS broadcast (4 addrs/wave)
      float raw  = fmaf(v, K.x, K.y);
      float draw = K.x;
      for (int m = 0; m < nmix; ++m) {           // wave-uniform trip count
        float4 M = sMix[m];
        float pj = fmaf(v, M.x, M.y);
        const int j = __float_as_int(M.z);
        float wjk = wl[(size_t)k * kWidth + j];  // w_kj (row k over j) -- FIXED
        bool on = pj > 0.0f;
        raw  = fmaf(on ? pj  : 0.0f, wjk, raw);
        draw = fmaf(on ? M.x : 0.0f, wjk, draw);
      }
      float h2 = fmaxf(raw, 0.0f);
      float dd = (raw > 0.0f) ? draw : 0.0f;
      o0 = fmaf(h2, K.z, o0);
      o1 = fmaf(h2, K.w, o1);
      p0 = fmaf(dd, K.z, p0);
      p1 = fmaf(dd, K.w, p1);
    }
    // reduce over the 4 kq lanes (consecutive lanes in-wave)
    o0 += __shfl_xor(o0, 1); o0 += __shfl_xor(o0, 2);
    o1 += __shfl_xor(o1, 1); o1 += __shfl_xor(o1, 2);
    p0 += __shfl_xor(p0, 1); p0 += __shfl_xor(p0, 2);
    p1 += __shfl_xor(p1, 1); p1 += __shfl_xor(p1, 2);
    if (kq == 0) {
      const float E0 = expf(lsf[layer*2 + 0]);
      const float E1 = expf(lsf[layer*2 + 1]);
      const float b30 = fc3_b[layer*2 + 0];
      const float b31 = fc3_b[layer*2 + 1];
      tab[(size_t)layer * tabN + node0 + node] =
          make_float4((o0 + b30) * E0, p0 * E0, (o1 + b31) * E1, p1 * E1);
    }
  }

  // sample-independent logdet constant
  if (blockIdx.x == 0 && t == 0) {
    float cst = 0.0f;
    for (int i = 0; i < kDepth; ++i) {
      cst -= logf(fabsf(an_scale[i*2+0]));
      cst -= logf(fabsf(an_scale[i*2+1]));
      const float* cw = conv_w + i * 4;
      float det = cw[0]*cw[3] - cw[1]*cw[2];
      cst += logf(fabsf(det));   // slogdet(conv)[1]
    }
    extra[0] = cst;
  }
}

// ---------------- main: per-sample 10-layer loop with two-line reconstruction ----------------
__global__ __launch_bounds__(256) void flow_apply_kernel(
    const float* __restrict__ x,
    const float* __restrict__ an_scale, const float* __restrict__ an_bias,
    const float* __restrict__ conv_w,
    const float4* __restrict__ tab, const float* __restrict__ extra,
    int tabN,
    float* __restrict__ out_z, float* __restrict__ out_ld, int n)
{
  int idx = blockIdx.x * blockDim.x + threadIdx.x;
  if (idx >= n) return;

  float2 z = reinterpret_cast<const float2*>(x)[idx];
  float ld = extra[0];
  const float dv = (kVMax - kVMin) / (float)(tabN - 1);
  const float inv_dv = (float)(tabN - 1) / (kVMax - kVMin);

#pragma unroll
  for (int i = 0; i < kDepth; ++i) {
    // actnorm
    float za = (z.x - an_bias[i*2+0]) / an_scale[i*2+0];
    float zb = (z.y - an_bias[i*2+1]) / an_scale[i*2+1];
    // 1x1 conv (2x2): z' = W z
    const float* cw = conv_w + i*4;
    float na = fmaf(cw[0], za, cw[1]*zb);
    float nb = fmaf(cw[2], za, cw[3]*zb);
    // table cell
    float xq = (nb - kVMin) * inv_dv;
    int qi = (int)floorf(xq);
    qi = qi < 0 ? 0 : (qi > tabN-2 ? tabN-2 : qi);
    float v0 = fmaf((float)qi, dv, kVMin);
    float v1 = v0 + dv;
    float4 e0 = tab[(size_t)i*tabN + qi];
    float4 e1 = tab[(size_t)i*tabN + qi + 1];
    // two-tangent-line reconstruction (exact for <=1 kink per cell)
    float tL = fmaf(nb - v0, e0.y, e0.x);
    float tR = fmaf(nb - v1, e1.y, e1.x);
    float tt = (e1.y >= e0.y) ? fmaxf(tL, tR) : fminf(tL, tR);
    float uL = fmaf(nb - v0, e0.w, e0.z);
    float uR = fmaf(nb - v1, e1.w, e1.z);
    float uu = (e1.w >= e0.w) ? fmaxf(uL, uR) : fminf(uL, uR);
    // exact sigmoid / log-sigmoid of arg = u + 2
    float arg = uu + 2.0f;
    float e = expf(-arg);
    float s = 1.0f / (1.0f + e);
    float lsv = -logf(1.0f + e);
    // coupling
    z.x = fmaf(s, na, tt);
    z.y = nb;
    ld += lsv;
  }

  reinterpret_cast<float2*>(out_z)[idx] = z;
  out_ld[idx] = ld;
}

extern "C" void kernel_launch(void* const* d_in, const int* in_sizes, int n_in,
                              void* d_out, int out_size, void* d_ws, size_t ws_size,
                              hipStream_t stream) {
  const float* x         = (const float*)d_in[0];
  const float* an_scale  = (const float*)d_in[1];
  const float* an_bias   = (const float*)d_in[2];
  const float* conv_w    = (const float*)d_in[3];
  const float* fc1_w     = (const float*)d_in[4];
  const float* fc1_b     = (const float*)d_in[5];
  const float* an1_scale = (const float*)d_in[6];
  const float* an1_bias  = (const float*)d_in[7];
  const float* fc2_w     = (const float*)d_in[8];
  const float* fc2_b     = (const float*)d_in[9];
  const float* an2_scale = (const float*)d_in[10];
  const float* an2_bias  = (const float*)d_in[11];
  const float* fc3_w     = (const float*)d_in[12];
  const float* fc3_b     = (const float*)d_in[13];
  const float* lsf       = (const float*)d_in[14];

  const int n = in_sizes[0] / 2;

  // workspace layout: [extra: 16 floats][table: float4 x kDepth x tabN]
  int tabN = 16384;
  while (tabN > 2048 &&
         (size_t)64 + (size_t)kDepth * tabN * sizeof(float4) > ws_size) {
    tabN >>= 1;
  }
  float* extra = (float*)d_ws;
  float4* tab  = (float4*)((char*)d_ws + 64);

  build_tables_kernel<<<kDepth * (tabN / 64), 256, 0, stream>>>(
      an_scale, conv_w, fc1_w, fc1_b, an1_scale, an1_bias,
      fc2_w, fc2_b, an2_scale, an2_bias, fc3_w, fc3_b, lsf, tabN, tab, extra);

  float* out_z  = (float*)d_out;
  float* out_ld = out_z + (size_t)2 * n;
  flow_apply_kernel<<<(n + 255) / 256, 256, 0, stream>>>(
      x, an_scale, an_bias, conv_w, tab, extra, tabN, out_z, out_ld, n);
}

// Round 9
// 96.313 us; speedup vs baseline: 3.0178x; 3.0178x over previous
//
#include <hip/hip_runtime.h>
#include <math.h>

// FlowLevel: DIM=2, half=1 -> per-layer coupling depends on scalar v = z_b.
// t(v) and u(v) (pre-sigmoid) are piecewise-LINEAR in v (ReLU MLP).
// Tabulate (t, dt/dv, u, du/dv) per node; apply reconstructs with two
// tangent lines (exact for <=1 kink per cell).
//
// Build v7: v6b + tail fix. Kinks are Cauchy-clustered at v~0, so central
// tiles have nmix~48; v6b's per-(node,k,m) divergent global loads made those
// ~10 blocks a 200us straggler tail (VALUBusy 4.5%, Occ 7.7%). Now the mixed
// columns are staged into LDS once per block (32 KB cap, global fallback for
// overflow), and phase-B uses interleaved k (kq+4i, consecutive banks) with
// i tiled by 4 so one sMix broadcast feeds 8 FMAs.

constexpr int kDepth = 10;
constexpr int kWidth = 128;
constexpr int kMixCap = 64;
constexpr float kVMin = -24.0f;
constexpr float kVMax =  24.0f;

__global__ __launch_bounds__(256) void build_tables_kernel(
    const float* __restrict__ an_scale,
    const float* __restrict__ conv_w,
    const float* __restrict__ fc1_w, const float* __restrict__ fc1_b,
    const float* __restrict__ an1_scale, const float* __restrict__ an1_bias,
    const float* __restrict__ fc2_w, const float* __restrict__ fc2_b,
    const float* __restrict__ an2_scale, const float* __restrict__ an2_bias,
    const float* __restrict__ fc3_w, const float* __restrict__ fc3_b,
    const float* __restrict__ lsf,
    int tabN,
    float4* __restrict__ tab, float* __restrict__ extra)
{
  __shared__ float  sGOn[128], sBOn[128];   // gated g / beta (0 unless fully-on)
  __shared__ float  sPc[128], sPe[128];     // phase-A partials (j-half 1)
  __shared__ float4 sK[128];                // per-k folded constants
  __shared__ float4 sMix[128];              // mixed-j list: (g, beta, j, -)
  __shared__ int    sCnt[2];
  __shared__ float  sWmix[kMixCap * 128];   // staged mixed columns (32 KB)

  const int bpl   = tabN >> 6;                 // tiles per layer
  const int layer = blockIdx.x / bpl;
  const int node0 = (blockIdx.x % bpl) * 64;
  const int t     = threadIdx.x;
  const float dv  = (kVMax - kVMin) / (float)(tabN - 1);
  const float vlo = kVMin + dv * (float)node0;
  const float vhi = kVMin + dv * (float)(node0 + 63);
  const float* wl = fc2_w + (size_t)layer * kWidth * kWidth;

  // ---- phase 0: gate classification + deterministic mixed-list scan ----
  bool mix = false; float g = 0.f, b = 0.f;
  if (t < 128) {
    const float s1 = an1_scale[layer*kWidth + t];
    g = fc1_w[layer*kWidth + t] / s1;
    b = (fc1_b[layer*kWidth + t] - an1_bias[layer*kWidth + t]) / s1;
    const bool onL = fmaf(vlo, g, b) > 0.0f;
    const bool onH = fmaf(vhi, g, b) > 0.0f;
    const bool full = onL && onH;
    mix = (onL != onH);
    sGOn[t] = full ? g : 0.0f;
    sBOn[t] = full ? b : 0.0f;
  }
  {
    const unsigned long long m = __ballot(mix);
    const int lane = t & 63, wv = t >> 6;
    const int pos = (int)__popcll(m & ((1ull << lane) - 1ull));
    if (wv < 2 && lane == 0) sCnt[wv] = (int)__popcll(m);
    __syncthreads();
    if (mix) sMix[(wv ? sCnt[0] : 0) + pos] = make_float4(g, b, __int_as_float(t), 0.0f);
  }
  __syncthreads();
  const int nmix = sCnt[0] + sCnt[1];
  const int nstage = nmix < kMixCap ? nmix : kMixCap;

  // ---- stage mixed columns into LDS (once per block) ----
  {
    const int k = t & 127, half = t >> 7;
    for (int m0 = 0; m0 < nstage; m0 += 2) {
      const int m = m0 + half;
      if (m < nstage) {
        const int j = __float_as_int(sMix[m].z);
        sWmix[m * 128 + k] = wl[(size_t)k * kWidth + j];
      }
    }
  }

  // ---- phase A: per-tile dots c_k, e_k over fully-on j ----
  {
    const int k = t & 127, jh = t >> 7;          // j-half 0: j 0..63, 1: 64..127
    const float4* wrow = (const float4*)(wl + (size_t)k * kWidth + jh * 64);
    float c = 0.0f, e = 0.0f;
#pragma unroll
    for (int jc = 0; jc < 16; ++jc) {
      float4 w  = wrow[jc];
      float4 g4 = ((const float4*)sGOn)[jh*16 + jc];
      float4 b4 = ((const float4*)sBOn)[jh*16 + jc];
      c = fmaf(g4.w, w.w, fmaf(g4.z, w.z, fmaf(g4.y, w.y, fmaf(g4.x, w.x, c))));
      e = fmaf(b4.w, w.w, fmaf(b4.z, w.z, fmaf(b4.y, w.y, fmaf(b4.x, w.x, e))));
    }
    if (jh) { sPc[k] = c; sPe[k] = e; }
    __syncthreads();
    if (t < 128) {
      c += sPc[t]; e += sPe[t];
      const float si = 1.0f / an2_scale[layer*kWidth + t];
      const float bz = fc2_b[layer*kWidth + t] - an2_bias[layer*kWidth + t];
      sK[t] = make_float4(c, e + bz,
                          fc3_w[layer*2*kWidth + t] * si,
                          fc3_w[layer*2*kWidth + kWidth + t] * si);
    }
  }
  __syncthreads();

  // ---- phase B: per-node evaluation; mixed corrections from LDS ----
  {
    const int node = t >> 2, kq = t & 3;         // 4 threads/node, interleaved k
    const float v = kVMin + dv * (float)(node0 + node);
    float o0 = 0.f, o1 = 0.f, p0 = 0.f, p1 = 0.f;
#pragma unroll 1
    for (int i4 = 0; i4 < 8; ++i4) {
      const int k0 = kq + 4 * (i4 * 4);          // +0,+4,+8,+12
      float4 K0 = sK[k0], K1 = sK[k0 + 4], K2 = sK[k0 + 8], K3 = sK[k0 + 12];
      float r0 = fmaf(v, K0.x, K0.y), d0 = K0.x;
      float r1 = fmaf(v, K1.x, K1.y), d1 = K1.x;
      float r2 = fmaf(v, K2.x, K2.y), d2 = K2.x;
      float r3 = fmaf(v, K3.x, K3.y), d3 = K3.x;
      for (int m = 0; m < nstage; ++m) {         // wave-uniform trip count
        float4 M = sMix[m];                      // broadcast
        float pj = fmaf(v, M.x, M.y);
        bool on = pj > 0.0f;
        float hp = on ? pj  : 0.0f;
        float hd = on ? M.x : 0.0f;
        const float* wm = &sWmix[m * 128 + k0];
        float w0 = wm[0], w1 = wm[4], w2 = wm[8], w3 = wm[12];
        r0 = fmaf(hp, w0, r0); d0 = fmaf(hd, w0, d0);
        r1 = fmaf(hp, w1, r1); d1 = fmaf(hd, w1, d1);
        r2 = fmaf(hp, w2, r2); d2 = fmaf(hd, w2, d2);
        r3 = fmaf(hp, w3, r3); d3 = fmaf(hd, w3, d3);
      }
      for (int m = nstage; m < nmix; ++m) {      // overflow fallback (rare)
        float4 M = sMix[m];
        float pj = fmaf(v, M.x, M.y);
        bool on = pj > 0.0f;
        float hp = on ? pj  : 0.0f;
        float hd = on ? M.x : 0.0f;
        const int j = __float_as_int(M.z);
        float w0 = wl[(size_t)(k0     ) * kWidth + j];
        float w1 = wl[(size_t)(k0 +  4) * kWidth + j];
        float w2 = wl[(size_t)(k0 +  8) * kWidth + j];
        float w3 = wl[(size_t)(k0 + 12) * kWidth + j];
        r0 = fmaf(hp, w0, r0); d0 = fmaf(hd, w0, d0);
        r1 = fmaf(hp, w1, r1); d1 = fmaf(hd, w1, d1);
        r2 = fmaf(hp, w2, r2); d2 = fmaf(hd, w2, d2);
        r3 = fmaf(hp, w3, r3); d3 = fmaf(hd, w3, d3);
      }
      float h, dd;
      h = fmaxf(r0, 0.f); dd = (r0 > 0.f) ? d0 : 0.f;
      o0 = fmaf(h, K0.z, o0); o1 = fmaf(h, K0.w, o1);
      p0 = fmaf(dd, K0.z, p0); p1 = fmaf(dd, K0.w, p1);
      h = fmaxf(r1, 0.f); dd = (r1 > 0.f) ? d1 : 0.f;
      o0 = fmaf(h, K1.z, o0); o1 = fmaf(h, K1.w, o1);
      p0 = fmaf(dd, K1.z, p0); p1 = fmaf(dd, K1.w, p1);
      h = fmaxf(r2, 0.f); dd = (r2 > 0.f) ? d2 : 0.f;
      o0 = fmaf(h, K2.z, o0); o1 = fmaf(h, K2.w, o1);
      p0 = fmaf(dd, K2.z, p0); p1 = fmaf(dd, K2.w, p1);
      h = fmaxf(r3, 0.f); dd = (r3 > 0.f) ? d3 : 0.f;
      o0 = fmaf(h, K3.z, o0); o1 = fmaf(h, K3.w, o1);
      p0 = fmaf(dd, K3.z, p0); p1 = fmaf(dd, K3.w, p1);
    }
    // reduce over the 4 kq lanes (adjacent in-wave)
    o0 += __shfl_xor(o0, 1); o0 += __shfl_xor(o0, 2);
    o1 += __shfl_xor(o1, 1); o1 += __shfl_xor(o1, 2);
    p0 += __shfl_xor(p0, 1); p0 += __shfl_xor(p0, 2);
    p1 += __shfl_xor(p1, 1); p1 += __shfl_xor(p1, 2);
    if (kq == 0) {
      const float E0 = expf(lsf[layer*2 + 0]);
      const float E1 = expf(lsf[layer*2 + 1]);
      const float b30 = fc3_b[layer*2 + 0];
      const float b31 = fc3_b[layer*2 + 1];
      tab[(size_t)layer * tabN + node0 + node] =
          make_float4((o0 + b30) * E0, p0 * E0, (o1 + b31) * E1, p1 * E1);
    }
  }

  // sample-independent logdet constant
  if (blockIdx.x == 0 && t == 0) {
    float cst = 0.0f;
    for (int i = 0; i < kDepth; ++i) {
      cst -= logf(fabsf(an_scale[i*2+0]));
      cst -= logf(fabsf(an_scale[i*2+1]));
      const float* cw = conv_w + i * 4;
      float det = cw[0]*cw[3] - cw[1]*cw[2];
      cst += logf(fabsf(det));   // slogdet(conv)[1]
    }
    extra[0] = cst;
  }
}

// ---------------- main: per-sample 10-layer loop with two-line reconstruction ----------------
__global__ __launch_bounds__(256) void flow_apply_kernel(
    const float* __restrict__ x,
    const float* __restrict__ an_scale, const float* __restrict__ an_bias,
    const float* __restrict__ conv_w,
    const float4* __restrict__ tab, const float* __restrict__ extra,
    int tabN,
    float* __restrict__ out_z, float* __restrict__ out_ld, int n)
{
  int idx = blockIdx.x * blockDim.x + threadIdx.x;
  if (idx >= n) return;

  float2 z = reinterpret_cast<const float2*>(x)[idx];
  float ld = extra[0];
  const float dv = (kVMax - kVMin) / (float)(tabN - 1);
  const float inv_dv = (float)(tabN - 1) / (kVMax - kVMin);

#pragma unroll
  for (int i = 0; i < kDepth; ++i) {
    // actnorm
    float za = (z.x - an_bias[i*2+0]) / an_scale[i*2+0];
    float zb = (z.y - an_bias[i*2+1]) / an_scale[i*2+1];
    // 1x1 conv (2x2): z' = W z
    const float* cw = conv_w + i*4;
    float na = fmaf(cw[0], za, cw[1]*zb);
    float nb = fmaf(cw[2], za, cw[3]*zb);
    // table cell
    float xq = (nb - kVMin) * inv_dv;
    int qi = (int)floorf(xq);
    qi = qi < 0 ? 0 : (qi > tabN-2 ? tabN-2 : qi);
    float v0 = fmaf((float)qi, dv, kVMin);
    float v1 = v0 + dv;
    float4 e0 = tab[(size_t)i*tabN + qi];
    float4 e1 = tab[(size_t)i*tabN + qi + 1];
    // two-tangent-line reconstruction (exact for <=1 kink per cell)
    float tL = fmaf(nb - v0, e0.y, e0.x);
    float tR = fmaf(nb - v1, e1.y, e1.x);
    float tt = (e1.y >= e0.y) ? fmaxf(tL, tR) : fminf(tL, tR);
    float uL = fmaf(nb - v0, e0.w, e0.z);
    float uR = fmaf(nb - v1, e1.w, e1.z);
    float uu = (e1.w >= e0.w) ? fmaxf(uL, uR) : fminf(uL, uR);
    // exact sigmoid / log-sigmoid of arg = u + 2
    float arg = uu + 2.0f;
    float e = expf(-arg);
    float s = 1.0f / (1.0f + e);
    float lsv = -logf(1.0f + e);
    // coupling
    z.x = fmaf(s, na, tt);
    z.y = nb;
    ld += lsv;
  }

  reinterpret_cast<float2*>(out_z)[idx] = z;
  out_ld[idx] = ld;
}

extern "C" void kernel_launch(void* const* d_in, const int* in_sizes, int n_in,
                              void* d_out, int out_size, void* d_ws, size_t ws_size,
                              hipStream_t stream) {
  const float* x         = (const float*)d_in[0];
  const float* an_scale  = (const float*)d_in[1];
  const float* an_bias   = (const float*)d_in[2];
  const float* conv_w    = (const float*)d_in[3];
  const float* fc1_w     = (const float*)d_in[4];
  const float* fc1_b     = (const float*)d_in[5];
  const float* an1_scale = (const float*)d_in[6];
  const float* an1_bias  = (const float*)d_in[7];
  const float* fc2_w     = (const float*)d_in[8];
  const float* fc2_b     = (const float*)d_in[9];
  const float* an2_scale = (const float*)d_in[10];
  const float* an2_bias  = (const float*)d_in[11];
  const float* fc3_w     = (const float*)d_in[12];
  const float* fc3_b     = (const float*)d_in[13];
  const float* lsf       = (const float*)d_in[14];

  const int n = in_sizes[0] / 2;

  // workspace layout: [extra: 16 floats][table: float4 x kDepth x tabN]
  int tabN = 16384;
  while (tabN > 2048 &&
         (size_t)64 + (size_t)kDepth * tabN * sizeof(float4) > ws_size) {
    tabN >>= 1;
  }
  float* extra = (float*)d_ws;
  float4* tab  = (float4*)((char*)d_ws + 64);

  build_tables_kernel<<<kDepth * (tabN / 64), 256, 0, stream>>>(
      an_scale, conv_w, fc1_w, fc1_b, an1_scale, an1_bias,
      fc2_w, fc2_b, an2_scale, an2_bias, fc3_w, fc3_b, lsf, tabN, tab, extra);

  float* out_z  = (float*)d_out;
  float* out_ld = out_z + (size_t)2 * n;
  flow_apply_kernel<<<(n + 255) / 256, 256, 0, stream>>>(
      x, an_scale, an_bias, conv_w, tab, extra, tabN, out_z, out_ld, n);
}